// Round 4
// baseline (379.710 us; speedup 1.0000x reference)
//
#include <hip/hip_runtime.h>
#include <hip/hip_bf16.h>

typedef __attribute__((ext_vector_type(4))) float f32x4;
typedef __attribute__((ext_vector_type(8))) short s16x8;

#define DEVINL __device__ __forceinline__

static constexpr int BB = 32, TT = 1024, DD = 512, EE = 256, VV = 50257, EXTRA = 200;
static constexpr int D2 = 1024;           // 2*D
static constexpr int VE = VV + EXTRA;     // 50457
static constexpr long MM = (long)BB * TT; // 32768

DEVINL unsigned short f2bf(float x) {
    union { float f; unsigned int u; } c; c.f = x;
    unsigned int u = c.u;
    u += 0x7fffu + ((u >> 16) & 1u);   // round-to-nearest-even
    return (unsigned short)(u >> 16);
}
DEVINL float sigmoidf_(float x) { return 1.0f / (1.0f + __expf(-x)); }
DEVINL float tanh_fast(float x) {
    x = fminf(15.f, fmaxf(-15.f, x));
    float e = __expf(2.f * x);
    return (e - 1.f) / (e + 1.f);
}
DEVINL void gl16(const void* g, void* l) {  // 16B global->LDS direct (dest: wave base + lane*16)
    __builtin_amdgcn_global_load_lds((__attribute__((address_space(1))) void*)g,
                                     (__attribute__((address_space(3))) void*)l, 16, 0, 0);
}

// ---------------------------------------------------------------- K0: W_h^T -> bf16, k-swizzled
// whtswz[n][k] = bf16(Wh[k ^ ((n&7)<<3)][n])   (XOR on k bits 3..5, G4 swizzle baked in)
__global__ void k_transpose_wh(const float* __restrict__ Wh, unsigned short* __restrict__ WhT) {
    __shared__ float tile[32][33];
    int n0 = blockIdx.x * 32, k0 = blockIdx.y * 32;
    int tx = threadIdx.x, ty = threadIdx.y;  // 32 x 8
    #pragma unroll
    for (int i = 0; i < 4; i++)
        tile[ty + i * 8][tx] = Wh[(long)(k0 + ty + i * 8) * D2 + n0 + tx];
    __syncthreads();
    #pragma unroll
    for (int i = 0; i < 4; i++) {
        int n = n0 + ty + i * 8;
        int kcol = (k0 + tx) ^ ((n & 7) << 3);
        WhT[(long)n * D2 + kcol] = f2bf(tile[tx][ty + i * 8]);
    }
}

// ---------------------------------------------------------------- K1: x = [pcv|emb] @ W_gx + b_gx
__global__ void k_x(const int* __restrict__ dec_in, const float* __restrict__ pcv,
                    const float* __restrict__ embt, const float* __restrict__ Wgx,
                    const float* __restrict__ bgx, float* __restrict__ xbuf) {
    __shared__ float xs[1280];
    __shared__ float sred[4][64];
    int b = blockIdx.x, n0 = blockIdx.y * 64;     // grid (32,4)
    int tid = threadIdx.x, nl = tid & 63, ks = tid >> 6;
    long er = (long)dec_in[b] * EE;
    for (int i = tid; i < 1280; i += 256)
        xs[i] = (i < 1024) ? pcv[b * 1024 + i] : embt[er + i - 1024];
    __syncthreads();
    float acc = 0.f;
    for (int k = ks * 320; k < ks * 320 + 320; ++k)
        acc += xs[k] * Wgx[(long)k * EE + n0 + nl];
    sred[ks][nl] = acc;
    __syncthreads();
    if (tid < 64) {
        int n = n0 + tid;
        xbuf[b * EE + n] = sred[0][tid] + sred[1][tid] + sred[2][tid] + sred[3][tid] + bgx[n];
    }
}

// ---------------------------------------------------------------- K2: LSTM cell (fused k-split)
__global__ void k_lstm(const float* __restrict__ xbuf, const float* __restrict__ h0,
                       const float* __restrict__ c0, const float* __restrict__ Wih,
                       const float* __restrict__ Whh, const float* __restrict__ bih,
                       const float* __restrict__ bhh, float* __restrict__ h1o,
                       float* __restrict__ c1o, float* __restrict__ dechat) {
    __shared__ float xs[768];
    __shared__ float sred[4][4][64];
    int b = blockIdx.x, d0 = blockIdx.y * 64;     // grid (32,8)
    int tid = threadIdx.x, dl = tid & 63, ks = tid >> 6;
    for (int i = tid; i < 768; i += 256)
        xs[i] = (i < 256) ? xbuf[b * 256 + i] : h0[b * 512 + i - 256];
    __syncthreads();
    float a0 = 0, a1 = 0, a2 = 0, a3 = 0;
    for (int k = ks * 192; k < ks * 192 + 192; ++k) {
        float xv = xs[k];
        const float* wr = (k < 256) ? (Wih + (long)k * 2048) : (Whh + (long)(k - 256) * 2048);
        a0 += xv * wr[d0 + dl];       a1 += xv * wr[512 + d0 + dl];
        a2 += xv * wr[1024 + d0 + dl]; a3 += xv * wr[1536 + d0 + dl];
    }
    sred[0][ks][dl] = a0; sred[1][ks][dl] = a1; sred[2][ks][dl] = a2; sred[3][ks][dl] = a3;
    __syncthreads();
    if (tid < 64) {
        int d = d0 + tid;
        float gi = bih[d] + bhh[d];
        float gf = bih[512 + d] + bhh[512 + d];
        float gg = bih[1024 + d] + bhh[1024 + d];
        float go = bih[1536 + d] + bhh[1536 + d];
        #pragma unroll
        for (int s = 0; s < 4; s++) {
            gi += sred[0][s][tid]; gf += sred[1][s][tid];
            gg += sred[2][s][tid]; go += sred[3][s][tid];
        }
        float c1 = sigmoidf_(gf) * c0[b * 512 + d] + sigmoidf_(gi) * tanh_fast(gg);
        float h1 = sigmoidf_(go) * tanh_fast(c1);
        h1o[b * 512 + d] = h1; c1o[b * 512 + d] = c1;
        dechat[b * 1024 + d] = h1; dechat[b * 1024 + 512 + d] = c1;
    }
}

// ---------------------------------------------------------------- K3: dec_feat = dec_hat @ W_s + b_s
__global__ void k_decfeat(const float* __restrict__ dechat, const float* __restrict__ Ws,
                          const float* __restrict__ bs, float* __restrict__ decfeat) {
    __shared__ float xs[1024];
    __shared__ float sred[4][64];
    int b = blockIdx.x, n0 = blockIdx.y * 64;     // grid (32,16)
    int tid = threadIdx.x, nl = tid & 63, ks = tid >> 6;
    for (int i = tid; i < 1024; i += 256) xs[i] = dechat[b * 1024 + i];
    __syncthreads();
    float acc = 0.f;
    for (int k = ks * 256; k < ks * 256 + 256; ++k)
        acc += xs[k] * Ws[(long)k * 1024 + n0 + nl];
    sred[ks][nl] = acc;
    __syncthreads();
    if (tid < 64) {
        int n = n0 + tid;
        decfeat[b * 1024 + n] = sred[0][tid] + sred[1][tid] + sred[2][tid] + sred[3][tid] + bs[n];
    }
}

// ---------------------------------------------------------------- K4: fused attention scores (pipelined)
// Per kt: issue B(kt+1) gl16 + A(kt+1) f32 loads FIRST, then MFMA kt, then barrier
// (drain overlaps compute), then cvt+ds_write A(kt+1).
__global__ __launch_bounds__(512) void k_scores(
    const float* __restrict__ enc, const unsigned short* __restrict__ whtswz,
    const float* __restrict__ decfeat, const float* __restrict__ cov,
    const float* __restrict__ Wc, const float* __restrict__ vvec,
    float* __restrict__ scorep) {
    __shared__ __align__(16) unsigned short As[128 * 64];     // 16 KB single buffer
    __shared__ __align__(16) unsigned short Bs[2][256 * 64];  // 64 KB double buffer
    // total 80 KB -> 2 blocks/CU; sred overlays As in epilogue
    const int tid = threadIdx.x;
    const int lane = tid & 63, wave = tid >> 6;
    const int wid = __builtin_amdgcn_readfirstlane(wave);
    const int g = lane >> 4, c = lane & 15;
    const int wm = wave >> 2, wn = wave & 3;   // 2 x 4 waves over 128m x 256n

    // XCD-chunked decode: the 4 nt-blocks of one m-tile are adjacent on the same XCD
    const int bid = blockIdx.x;
    const int xcd = bid & 7, t = bid >> 3;
    const int mt = xcd * 32 + (t >> 2), nt = t & 3;
    const long m0 = (long)mt * 128;
    const int n0 = nt * 256;
    const int bblk = mt >> 3;                  // batch row

    // A staging mapping: thread -> row ar (4 thr/row), 16-float chunk ac16
    const int ar = tid >> 2, ac16 = (tid & 3) * 16;
    const int asx = (ar & 7) << 3;
    // B staging: per wave 32 rows via 4 gl16
    const int brow = wid * 32 + (lane >> 3);
    const int bxo  = (lane & 7) * 8;

    f32x4 acc[4][4];
    #pragma unroll
    for (int i = 0; i < 4; i++)
        #pragma unroll
        for (int j = 0; j < 4; j++) acc[i][j] = (f32x4){0.f, 0.f, 0.f, 0.f};

    const int sx = (c & 7) << 3;               // read-side swizzle

    // ---- prologue: stage kt=0
    {
        unsigned short* bBase = &Bs[0][wid * 2048];
        gl16(whtswz + (long)(n0 + brow) * 1024 + bxo,        bBase);
        gl16(whtswz + (long)(n0 + brow + 8) * 1024 + bxo,    bBase + 512);
        gl16(whtswz + (long)(n0 + brow + 16) * 1024 + bxo,   bBase + 1024);
        gl16(whtswz + (long)(n0 + brow + 24) * 1024 + bxo,   bBase + 1536);
        const float* src = enc + (m0 + ar) * 1024 + ac16;
        f32x4 a0 = ((const f32x4*)src)[0];
        f32x4 a1 = ((const f32x4*)src)[1];
        f32x4 a2 = ((const f32x4*)src)[2];
        f32x4 a3 = ((const f32x4*)src)[3];
        s16x8 p0, p1;
        p0[0] = (short)f2bf(a0[0]); p0[1] = (short)f2bf(a0[1]);
        p0[2] = (short)f2bf(a0[2]); p0[3] = (short)f2bf(a0[3]);
        p0[4] = (short)f2bf(a1[0]); p0[5] = (short)f2bf(a1[1]);
        p0[6] = (short)f2bf(a1[2]); p0[7] = (short)f2bf(a1[3]);
        p1[0] = (short)f2bf(a2[0]); p1[1] = (short)f2bf(a2[1]);
        p1[2] = (short)f2bf(a2[2]); p1[3] = (short)f2bf(a2[3]);
        p1[4] = (short)f2bf(a3[0]); p1[5] = (short)f2bf(a3[1]);
        p1[6] = (short)f2bf(a3[2]); p1[7] = (short)f2bf(a3[3]);
        *(s16x8*)&As[ar * 64 + (ac16 ^ asx)]       = p0;
        *(s16x8*)&As[ar * 64 + ((ac16 + 8) ^ asx)] = p1;
    }
    __syncthreads();

    for (int kt = 0; kt < 16; ++kt) {
        f32x4 a0, a1, a2, a3;
        const bool more = (kt < 15);
        if (more) {
            const int k1 = (kt + 1) * 64;
            unsigned short* bBase = &Bs[(kt + 1) & 1][wid * 2048];
            gl16(whtswz + (long)(n0 + brow) * 1024 + k1 + bxo,        bBase);
            gl16(whtswz + (long)(n0 + brow + 8) * 1024 + k1 + bxo,    bBase + 512);
            gl16(whtswz + (long)(n0 + brow + 16) * 1024 + k1 + bxo,   bBase + 1024);
            gl16(whtswz + (long)(n0 + brow + 24) * 1024 + k1 + bxo,   bBase + 1536);
            const float* src = enc + (m0 + ar) * 1024 + k1 + ac16;
            a0 = ((const f32x4*)src)[0];
            a1 = ((const f32x4*)src)[1];
            a2 = ((const f32x4*)src)[2];
            a3 = ((const f32x4*)src)[3];
        }
        // ---- compute kt
        const unsigned short* bs_ = Bs[kt & 1];
        __builtin_amdgcn_s_setprio(1);
        #pragma unroll
        for (int kk = 0; kk < 2; ++kk) {
            const int kse = (kk * 32 + g * 8) ^ sx;
            s16x8 af[4], bfj[4];
            #pragma unroll
            for (int i = 0; i < 4; i++) af[i] = *(const s16x8*)&As[(wm * 64 + i * 16 + c) * 64 + kse];
            #pragma unroll
            for (int j = 0; j < 4; j++) bfj[j] = *(const s16x8*)&bs_[(wn * 64 + j * 16 + c) * 64 + kse];
            #pragma unroll
            for (int i = 0; i < 4; i++)
                #pragma unroll
                for (int j = 0; j < 4; j++)
                    acc[i][j] = __builtin_amdgcn_mfma_f32_16x16x32_bf16(af[i], bfj[j], acc[i][j], 0, 0, 0);
        }
        __builtin_amdgcn_s_setprio(0);
        __syncthreads();   // drains vmcnt: B(kt+1) in LDS, A-regs valid; As reads complete
        if (more) {
            s16x8 p0, p1;
            p0[0] = (short)f2bf(a0[0]); p0[1] = (short)f2bf(a0[1]);
            p0[2] = (short)f2bf(a0[2]); p0[3] = (short)f2bf(a0[3]);
            p0[4] = (short)f2bf(a1[0]); p0[5] = (short)f2bf(a1[1]);
            p0[6] = (short)f2bf(a1[2]); p0[7] = (short)f2bf(a1[3]);
            p1[0] = (short)f2bf(a2[0]); p1[1] = (short)f2bf(a2[1]);
            p1[2] = (short)f2bf(a2[2]); p1[3] = (short)f2bf(a2[3]);
            p1[4] = (short)f2bf(a3[0]); p1[5] = (short)f2bf(a3[1]);
            p1[6] = (short)f2bf(a3[2]); p1[7] = (short)f2bf(a3[3]);
            *(s16x8*)&As[ar * 64 + (ac16 ^ asx)]       = p0;
            *(s16x8*)&As[ar * 64 + ((ac16 + 8) ^ asx)] = p1;
            __syncthreads();   // LDS-only ordering for As
        }
    }

    // ---- fused epilogue: v-weighted tanh partial sums for this nt
    float dfv[4], wcv[4], vvj[4];
    #pragma unroll
    for (int j = 0; j < 4; j++) {
        int col = n0 + wn * 64 + j * 16 + c;
        dfv[j] = decfeat[bblk * D2 + col];
        wcv[j] = Wc[col];
        vvj[j] = vvec[col];
    }
    float sAcc[4][4];
    #pragma unroll
    for (int i = 0; i < 4; i++) {
        #pragma unroll
        for (int r = 0; r < 4; r++) {
            const long m = m0 + wm * 64 + i * 16 + g * 4 + r;
            const float covm = cov[m];
            float su = 0.f;
            #pragma unroll
            for (int j = 0; j < 4; j++) {
                float e = acc[i][j][r] + dfv[j] + covm * wcv[j];
                su += tanh_fast(e) * vvj[j];
            }
            su += __shfl_xor(su, 1); su += __shfl_xor(su, 2);
            su += __shfl_xor(su, 4); su += __shfl_xor(su, 8);
            sAcc[i][r] = su;
        }
    }
    float (*sred)[128] = (float(*)[128])As;    // overlay (As dead after k-loop)
    if (c == 0) {
        #pragma unroll
        for (int i = 0; i < 4; i++)
            #pragma unroll
            for (int r = 0; r < 4; r++)
                sred[wn][wm * 64 + i * 16 + g * 4 + r] = sAcc[i][r];
    }
    __syncthreads();
    if (tid < 128)
        scorep[(long)nt * MM + m0 + tid] = sred[0][tid] + sred[1][tid] + sred[2][tid] + sred[3][tid];
}

// ---------------------------------------------------------------- K5: softmax + mask renorm
__global__ void k_softmax(const float* __restrict__ scorep, const float* __restrict__ mask,
                          const float* __restrict__ cov, float* __restrict__ att,
                          float* __restrict__ covn) {
    int b = blockIdx.x, tid = threadIdx.x;  // 256 threads
    __shared__ float sm[8];
    float sv[4];
    float mx = -1e30f;
    #pragma unroll
    for (int i = 0; i < 4; i++) {
        long idx = (long)b * TT + tid + 256 * i;
        sv[i] = scorep[idx] + scorep[MM + idx] + scorep[2 * MM + idx] + scorep[3 * MM + idx];
        mx = fmaxf(mx, sv[i]);
    }
    for (int o = 32; o; o >>= 1) mx = fmaxf(mx, __shfl_xor(mx, o));
    if ((tid & 63) == 0) sm[tid >> 6] = mx;
    __syncthreads();
    mx = fmaxf(fmaxf(sm[0], sm[1]), fmaxf(sm[2], sm[3]));
    __syncthreads();
    float e[4]; float s = 0.f;
    #pragma unroll
    for (int i = 0; i < 4; i++) { e[i] = __expf(sv[i] - mx); s += e[i]; }
    for (int o = 32; o; o >>= 1) s += __shfl_xor(s, o);
    if ((tid & 63) == 0) sm[tid >> 6] = s;
    __syncthreads();
    s = sm[0] + sm[1] + sm[2] + sm[3];
    __syncthreads();
    float inv = 1.f / s;
    float am[4]; float s2 = 0.f;
    #pragma unroll
    for (int i = 0; i < 4; i++) { am[i] = e[i] * inv * mask[b * TT + tid + 256 * i]; s2 += am[i]; }
    for (int o = 32; o; o >>= 1) s2 += __shfl_xor(s2, o);
    if ((tid & 63) == 0) sm[tid >> 6] = s2;
    __syncthreads();
    s2 = sm[0] + sm[1] + sm[2] + sm[3];
    float inv2 = 1.f / s2;
    #pragma unroll
    for (int i = 0; i < 4; i++) {
        int t = tid + 256 * i;
        float a = am[i] * inv2;
        att[b * TT + t] = a;
        covn[b * TT + t] = cov[b * TT + t] + a;
    }
}

// ---------------------------------------------------------------- K6: context partials + reduce
__global__ void k_context(const float* __restrict__ enc, const float* __restrict__ att,
                          float* __restrict__ part) {
    int b = blockIdx.x, tc = blockIdx.y;  // grid (32,16)
    int d4 = threadIdx.x;                 // 256 threads -> d = d4*4
    float a0 = 0, a1 = 0, a2 = 0, a3 = 0;
    const float* ab = att + b * TT;
    for (int t = tc * 64; t < tc * 64 + 64; ++t) {
        float a = ab[t];
        f32x4 ev = *(const f32x4*)(enc + ((long)b * TT + t) * D2 + d4 * 4);
        a0 += a * ev[0]; a1 += a * ev[1]; a2 += a * ev[2]; a3 += a * ev[3];
    }
    float* pp = part + (long)tc * BB * D2 + b * D2 + d4 * 4;
    pp[0] = a0; pp[1] = a1; pp[2] = a2; pp[3] = a3;
}

__global__ void k_ctxreduce(const float* __restrict__ part, float* __restrict__ ctx) {
    int i = blockIdx.x * 256 + threadIdx.x;  // 128 blocks
    float s = 0.f;
    #pragma unroll
    for (int p = 0; p < 16; p++) s += part[(long)p * BB * D2 + i];
    ctx[i] = s;
}

// ---------------------------------------------------------------- K7a: p_gen
__global__ void k_pgen(const float* __restrict__ ctx, const float* __restrict__ dechat,
                       const float* __restrict__ xbuf, const float* __restrict__ Wpg,
                       const float* __restrict__ bpg, float* __restrict__ pgen) {
    int b = blockIdx.x, tid = threadIdx.x;  // 256 threads
    __shared__ float sm[8];
    float acc = 0.f;
    for (int k = tid; k < D2; k += 256)
        acc += ctx[b * D2 + k] * Wpg[k] + dechat[b * D2 + k] * Wpg[D2 + k];
    acc += xbuf[b * EE + tid] * Wpg[2 * D2 + tid];
    for (int o = 32; o; o >>= 1) acc += __shfl_xor(acc, o);
    if ((tid & 63) == 0) sm[tid >> 6] = acc;
    __syncthreads();
    if (tid == 0) {
        float t = sm[0] + sm[1] + sm[2] + sm[3];
        pgen[b] = sigmoidf_(t + bpg[0]);
    }
}

// ---------------------------------------------------------------- K7b: hiddenT = ([h1|ctx] @ W_v1 + b_v1)^T
__global__ void k_hidden(const float* __restrict__ h1, const float* __restrict__ ctx,
                         const float* __restrict__ Wv1, const float* __restrict__ bv1,
                         float* __restrict__ hiddenT) {
    __shared__ float xs[1536];
    __shared__ float sred[4][64];
    int b = blockIdx.x, n0 = blockIdx.y * 64;   // grid (32,8)
    int tid = threadIdx.x, nl = tid & 63, ks = tid >> 6;
    for (int i = tid; i < 1536; i += 256)
        xs[i] = (i < 512) ? h1[b * 512 + i] : ctx[b * 1024 + i - 512];
    __syncthreads();
    float acc = 0.f;
    for (int k = ks * 384; k < ks * 384 + 384; ++k)
        acc += xs[k] * Wv1[(long)k * 512 + n0 + nl];
    sred[ks][nl] = acc;
    __syncthreads();
    if (tid < 64) {
        int n = n0 + tid;
        float val = sred[0][tid] + sred[1][tid] + sred[2][tid] + sred[3][tid] + bv1[n];
        hiddenT[n * 32 + b] = val;     // [k][b] layout for k_logits s_load path
    }
}

// ---------------------------------------------------------------- K8: logits = hidden @ W_v2 + b_v2
// 1 wave/block, lane = one v column, acc[32] in VGPRs, hiddenT via uniform (scalar) loads.
__global__ __launch_bounds__(64) void k_logits(const float* __restrict__ hiddenT,
                                               const float* __restrict__ Wv2,
                                               const float* __restrict__ bv2,
                                               float* __restrict__ logits) {
    int v = blockIdx.x * 64 + threadIdx.x;
    if (v >= VV) return;
    float acc[32];
    float bv = bv2[v];
    #pragma unroll
    for (int i = 0; i < 32; i++) acc[i] = bv;
    const float* wp = Wv2 + v;
    #pragma unroll 8
    for (int k = 0; k < 512; ++k) {
        float w = wp[(long)k * VV];
        const float* h = hiddenT + k * 32;   // block-uniform -> s_load
        #pragma unroll
        for (int b = 0; b < 32; b++) acc[b] += h[b] * w;
    }
    #pragma unroll
    for (int b = 0; b < 32; b++) logits[(long)b * VV + v] = acc[b];
}

// ---------------------------------------------------------------- K9: fused rowstats + vocab_final + scatter
__global__ __launch_bounds__(1024) void k_vocab_all(
    const float* __restrict__ logits, const float* __restrict__ pgen,
    const float* __restrict__ extraz, const float* __restrict__ att,
    const int* __restrict__ eiv, float* __restrict__ out0) {
    int b = blockIdx.x, tid = threadIdx.x;   // 32 blocks x 1024 thr
    __shared__ float sm[16];
    const float* lr = logits + (long)b * VV;
    float mx = -1e30f;
    for (int v = tid; v < VV; v += 1024) mx = fmaxf(mx, lr[v]);
    for (int o = 32; o; o >>= 1) mx = fmaxf(mx, __shfl_xor(mx, o));
    if ((tid & 63) == 0) sm[tid >> 6] = mx;
    __syncthreads();
    #pragma unroll
    for (int i = 0; i < 16; i++) mx = fmaxf(mx, sm[i]);
    __syncthreads();
    float s = 0.f;
    for (int v = tid; v < VV; v += 1024) s += __expf(lr[v] - mx);
    for (int o = 32; o; o >>= 1) s += __shfl_xor(s, o);
    if ((tid & 63) == 0) sm[tid >> 6] = s;
    __syncthreads();
    s = 0.f;
    #pragma unroll
    for (int i = 0; i < 16; i++) s += sm[i];
    float pg = pgen[b];
    float inv = pg / s;
    float* orow = out0 + (long)b * VE;
    for (int v = tid; v < VV; v += 1024) orow[v] = __expf(lr[v] - mx) * inv;
    if (tid < EXTRA) orow[VV + tid] = extraz[b * EXTRA + tid];
    __syncthreads();
    // pointer scatter (TT == 1024 == blockDim)
    float a = (1.f - pg) * att[b * TT + tid];
    atomicAdd(orow + eiv[b * TT + tid], a);
}

// ================================================================ host
extern "C" void kernel_launch(void* const* d_in, const int* in_sizes, int n_in,
                              void* d_out, int out_size, void* d_ws, size_t ws_size,
                              hipStream_t stream) {
    const int*   dec_in = (const int*)d_in[0];
    const float* h0     = (const float*)d_in[1];
    const float* c0     = (const float*)d_in[2];
    const float* enc    = (const float*)d_in[3];
    const float* mask   = (const float*)d_in[4];
    const float* pcv    = (const float*)d_in[5];
    const float* cov    = (const float*)d_in[6];
    const float* extraz = (const float*)d_in[7];
    const int*   eiv    = (const int*)d_in[8];
    /* d_in[9] = step (unused, training path) */
    const float* embt   = (const float*)d_in[10];
    const float* Wgx    = (const float*)d_in[11];
    const float* bgx    = (const float*)d_in[12];
    const float* Wih    = (const float*)d_in[13];
    const float* Whh    = (const float*)d_in[14];
    const float* bih    = (const float*)d_in[15];
    const float* bhh    = (const float*)d_in[16];
    const float* Wh     = (const float*)d_in[17];
    const float* Wc     = (const float*)d_in[18];
    const float* Ws     = (const float*)d_in[19];
    const float* bs     = (const float*)d_in[20];
    const float* vv     = (const float*)d_in[21];
    const float* Wpg    = (const float*)d_in[22];
    const float* bpg    = (const float*)d_in[23];
    const float* Wv1    = (const float*)d_in[24];
    const float* bv1    = (const float*)d_in[25];
    const float* Wv2    = (const float*)d_in[26];
    const float* bv2    = (const float*)d_in[27];

    float* out = (float*)d_out;
    float* out_vd  = out;
    float* out_h1  = out + (long)BB * VE;
    float* out_c1  = out_h1 + BB * DD;
    float* out_ctx = out_c1 + BB * DD;
    float* out_att = out_ctx + BB * D2;
    float* out_cov = out_att + BB * TT;

    char* p = (char*)d_ws;
    unsigned short* whtswz = (unsigned short*)p; p += (size_t)D2 * D2 * 2;      // 2 MB
    float* xbuf    = (float*)p;  p += (size_t)BB * EE * 4;
    float* dechat  = (float*)p;  p += (size_t)BB * D2 * 4;
    float* decfeat = (float*)p;  p += (size_t)BB * D2 * 4;
    float* scorep  = (float*)p;  p += (size_t)4 * MM * 4;                        // 512 KB
    float* pgen    = (float*)p;  p += 256;
    float* hiddenT = (float*)p;  p += (size_t)BB * DD * 4;
    float* stats   = (float*)p;  p += 256; (void)stats;
    float* ctxpart = (float*)p;  p += (size_t)16 * BB * D2 * 4;                  // 2 MB
    float* logits  = (float*)p;  p += (size_t)BB * VV * 4;                       // 6.43 MB

    k_transpose_wh<<<dim3(32, 32), dim3(32, 8), 0, stream>>>(Wh, whtswz);
    k_x<<<dim3(BB, 4), 256, 0, stream>>>(dec_in, pcv, embt, Wgx, bgx, xbuf);
    k_lstm<<<dim3(BB, 8), 256, 0, stream>>>(xbuf, h0, c0, Wih, Whh, bih, bhh, out_h1, out_c1, dechat);
    k_decfeat<<<dim3(BB, 16), 256, 0, stream>>>(dechat, Ws, bs, decfeat);
    k_scores<<<1024, 512, 0, stream>>>(enc, whtswz, decfeat, cov, Wc, vv, scorep);
    k_softmax<<<BB, 256, 0, stream>>>(scorep, mask, cov, out_att, out_cov);
    k_context<<<dim3(BB, 16), 256, 0, stream>>>(enc, out_att, ctxpart);
    k_ctxreduce<<<(BB * D2) / 256, 256, 0, stream>>>(ctxpart, out_ctx);
    k_pgen<<<BB, 256, 0, stream>>>(out_ctx, dechat, xbuf, Wpg, bpg, pgen);
    k_hidden<<<dim3(BB, 8), 256, 0, stream>>>(out_h1, out_ctx, Wv1, bv1, hiddenT);
    k_logits<<<786, 64, 0, stream>>>(hiddenT, Wv2, bv2, logits);
    k_vocab_all<<<BB, 1024, 0, stream>>>(logits, pgen, extraz, out_att, eiv, out_vd);
}

// Round 5
// 320.272 us; speedup vs baseline: 1.1856x; 1.1856x over previous
//
#include <hip/hip_runtime.h>
#include <hip/hip_bf16.h>

typedef __attribute__((ext_vector_type(4))) float f32x4;
typedef __attribute__((ext_vector_type(8))) short s16x8;
typedef __attribute__((ext_vector_type(4))) short s16x4;

#define DEVINL __device__ __forceinline__

static constexpr int BB = 32, TT = 1024, DD = 512, EE = 256, VV = 50257, EXTRA = 200;
static constexpr int D2 = 1024;           // 2*D
static constexpr int VE = VV + EXTRA;     // 50457
static constexpr long MM = (long)BB * TT; // 32768

DEVINL unsigned short f2bf(float x) {
    union { float f; unsigned int u; } c; c.f = x;
    unsigned int u = c.u;
    u += 0x7fffu + ((u >> 16) & 1u);   // round-to-nearest-even
    return (unsigned short)(u >> 16);
}
DEVINL float bf2f(unsigned short h) {
    union { unsigned int u; float f; } c; c.u = ((unsigned int)h) << 16;
    return c.f;
}
DEVINL float sigmoidf_(float x) { return 1.0f / (1.0f + __expf(-x)); }
DEVINL float tanh_fast(float x) {
    x = fminf(15.f, fmaxf(-15.f, x));
    float e = __expf(2.f * x);
    return (e - 1.f) / (e + 1.f);
}
DEVINL void gl16(const void* g, void* l) {  // 16B global->LDS direct (dest: wave base + lane*16)
    __builtin_amdgcn_global_load_lds((__attribute__((address_space(1))) void*)g,
                                     (__attribute__((address_space(3))) void*)l, 16, 0, 0);
}

// ---------------------------------------------------------------- K0: W_h^T -> bf16, k-swizzled
// whtswz[n][k] = bf16(Wh[k ^ ((n&7)<<3)][n])
__global__ void k_transpose_wh(const float* __restrict__ Wh, unsigned short* __restrict__ WhT) {
    __shared__ float tile[32][33];
    int n0 = blockIdx.x * 32, k0 = blockIdx.y * 32;
    int tx = threadIdx.x, ty = threadIdx.y;  // 32 x 8
    #pragma unroll
    for (int i = 0; i < 4; i++)
        tile[ty + i * 8][tx] = Wh[(long)(k0 + ty + i * 8) * D2 + n0 + tx];
    __syncthreads();
    #pragma unroll
    for (int i = 0; i < 4; i++) {
        int n = n0 + ty + i * 8;
        int kcol = (k0 + tx) ^ ((n & 7) << 3);
        WhT[(long)n * D2 + kcol] = f2bf(tile[tx][ty + i * 8]);
    }
}

// ---------------------------------------------------------------- K0b: enc f32 -> bf16, k-swizzled
// encswz[m][k] = bf16(enc[m][k ^ ((m&7)<<3)])
__global__ void k_enc2bf(const float* __restrict__ enc, unsigned short* __restrict__ dst) {
    long idx = (long)blockIdx.x * 256 + threadIdx.x;  // 16384 blocks
    int m  = (int)(idx >> 7);
    int k2 = (int)(idx & 127) * 8;
    int s  = (m & 7) << 3;
    const float* src = enc + (long)m * 1024 + (k2 ^ s);
    f32x4 a = *(const f32x4*)src;
    f32x4 b = *(const f32x4*)(src + 4);
    s16x8 h;
    h[0] = (short)f2bf(a[0]); h[1] = (short)f2bf(a[1]); h[2] = (short)f2bf(a[2]); h[3] = (short)f2bf(a[3]);
    h[4] = (short)f2bf(b[0]); h[5] = (short)f2bf(b[1]); h[6] = (short)f2bf(b[2]); h[7] = (short)f2bf(b[3]);
    *(s16x8*)(dst + (long)m * 1024 + k2) = h;
}

// ---------------------------------------------------------------- K1: x = [pcv|emb] @ W_gx + b_gx
__global__ __launch_bounds__(512) void k_x(
    const int* __restrict__ dec_in, const float* __restrict__ pcv,
    const float* __restrict__ embt, const float* __restrict__ Wgx,
    const float* __restrict__ bgx, float* __restrict__ xbuf) {
    __shared__ float xs[1280];
    __shared__ float sred[8][64];
    int b = blockIdx.x, n0 = blockIdx.y * 64;     // grid (32,4)
    int tid = threadIdx.x, nl = tid & 63, ks = tid >> 6;   // 8 k-slices x 160
    long er = (long)dec_in[b] * EE;
    for (int i = tid; i < 1280; i += 512)
        xs[i] = (i < 1024) ? pcv[b * 1024 + i] : embt[er + i - 1024];
    __syncthreads();
    float acc = 0.f;
    for (int k = ks * 160; k < ks * 160 + 160; ++k)
        acc += xs[k] * Wgx[(long)k * EE + n0 + nl];
    sred[ks][nl] = acc;
    __syncthreads();
    if (tid < 64) {
        int n = n0 + tid;
        float s = bgx[n];
        #pragma unroll
        for (int i = 0; i < 8; i++) s += sred[i][tid];
        xbuf[b * EE + n] = s;
    }
}

// ---------------------------------------------------------------- K2: LSTM cell (fused k-split)
__global__ __launch_bounds__(512) void k_lstm(
    const float* __restrict__ xbuf, const float* __restrict__ h0,
    const float* __restrict__ c0, const float* __restrict__ Wih,
    const float* __restrict__ Whh, const float* __restrict__ bih,
    const float* __restrict__ bhh, float* __restrict__ h1o,
    float* __restrict__ c1o, float* __restrict__ dechat) {
    __shared__ float xs[768];
    __shared__ float sred[4][8][64];
    int b = blockIdx.x, d0 = blockIdx.y * 64;     // grid (32,8)
    int tid = threadIdx.x, dl = tid & 63, ks = tid >> 6;   // 8 k-slices x 96
    for (int i = tid; i < 768; i += 512)
        xs[i] = (i < 256) ? xbuf[b * 256 + i] : h0[b * 512 + i - 256];
    __syncthreads();
    float a0 = 0, a1 = 0, a2 = 0, a3 = 0;
    for (int k = ks * 96; k < ks * 96 + 96; ++k) {
        float xv = xs[k];
        const float* wr = (k < 256) ? (Wih + (long)k * 2048) : (Whh + (long)(k - 256) * 2048);
        a0 += xv * wr[d0 + dl];        a1 += xv * wr[512 + d0 + dl];
        a2 += xv * wr[1024 + d0 + dl]; a3 += xv * wr[1536 + d0 + dl];
    }
    sred[0][ks][dl] = a0; sred[1][ks][dl] = a1; sred[2][ks][dl] = a2; sred[3][ks][dl] = a3;
    __syncthreads();
    if (tid < 64) {
        int d = d0 + tid;
        float gi = bih[d] + bhh[d];
        float gf = bih[512 + d] + bhh[512 + d];
        float gg = bih[1024 + d] + bhh[1024 + d];
        float go = bih[1536 + d] + bhh[1536 + d];
        #pragma unroll
        for (int s = 0; s < 8; s++) {
            gi += sred[0][s][tid]; gf += sred[1][s][tid];
            gg += sred[2][s][tid]; go += sred[3][s][tid];
        }
        float c1 = sigmoidf_(gf) * c0[b * 512 + d] + sigmoidf_(gi) * tanh_fast(gg);
        float h1 = sigmoidf_(go) * tanh_fast(c1);
        h1o[b * 512 + d] = h1; c1o[b * 512 + d] = c1;
        dechat[b * 1024 + d] = h1; dechat[b * 1024 + 512 + d] = c1;
    }
}

// ---------------------------------------------------------------- K3: dec_feat = dec_hat @ W_s + b_s
__global__ __launch_bounds__(512) void k_decfeat(
    const float* __restrict__ dechat, const float* __restrict__ Ws,
    const float* __restrict__ bs, float* __restrict__ decfeat) {
    __shared__ float xs[1024];
    __shared__ float sred[8][64];
    int b = blockIdx.x, n0 = blockIdx.y * 64;     // grid (32,16)
    int tid = threadIdx.x, nl = tid & 63, ks = tid >> 6;   // 8 x 128
    for (int i = tid; i < 1024; i += 512) xs[i] = dechat[b * 1024 + i];
    __syncthreads();
    float acc = 0.f;
    for (int k = ks * 128; k < ks * 128 + 128; ++k)
        acc += xs[k] * Ws[(long)k * 1024 + n0 + nl];
    sred[ks][nl] = acc;
    __syncthreads();
    if (tid < 64) {
        int n = n0 + tid;
        float s = bs[n];
        #pragma unroll
        for (int i = 0; i < 8; i++) s += sred[i][tid];
        decfeat[b * 1024 + n] = s;
    }
}

// ---------------------------------------------------------------- K4: fused attention scores (R2 structure)
// scorep[nt][m] = sum_{j in nt-chunk} v[j]*tanh( (enc@W_h)[m,j] + dec_feat[b,j] + cov[m]*W_c[j] )
__global__ __launch_bounds__(512) void k_scores(
    const unsigned short* __restrict__ encswz, const unsigned short* __restrict__ whtswz,
    const float* __restrict__ decfeat, const float* __restrict__ cov,
    const float* __restrict__ Wc, const float* __restrict__ vvec,
    float* __restrict__ scorep) {
    __shared__ __align__(16) unsigned short As[128 * 64];   // 16 KB, linear, data pre-swizzled
    __shared__ __align__(16) unsigned short Bs[256 * 64];   // 32 KB
    __shared__ float sred[4][128];                          // total 50 KB -> 3 blocks/CU
    const int tid = threadIdx.x;
    const int lane = tid & 63, wave = tid >> 6;
    const int wid = __builtin_amdgcn_readfirstlane(wave);
    const int g = lane >> 4, c = lane & 15;
    const int wm = wave >> 2, wn = wave & 3;   // 2 x 4 waves over 128m x 256n

    // XCD-chunked decode: the 4 nt-blocks of one m-tile are adjacent on the same XCD
    const int bid = blockIdx.x;
    const int xcd = bid & 7, t = bid >> 3;
    const int mt = xcd * 32 + (t >> 2), nt = t & 3;
    const long m0 = (long)mt * 128;
    const int n0 = nt * 256;
    const int bblk = mt >> 3;                  // batch row

    // staging geometry: per wave A covers 16 rows (2 gl16 x 8), B covers 32 rows (4 gl16 x 8)
    const int arow = wid * 16 + (lane >> 3);
    const int axo  = (lane & 7) * 8;
    const int brow = wid * 32 + (lane >> 3);
    unsigned short* aBase = &As[wid * 1024];
    unsigned short* bBase = &Bs[wid * 2048];

    f32x4 acc[4][4];
    #pragma unroll
    for (int i = 0; i < 4; i++)
        #pragma unroll
        for (int j = 0; j < 4; j++) acc[i][j] = (f32x4){0.f, 0.f, 0.f, 0.f};

    const int sx = (c & 7) << 3;               // read-side swizzle (matches baked source swizzle)

    for (int kt = 0; kt < 16; ++kt) {
        const int k0 = kt * 64;
        __syncthreads();
        gl16(encswz + (m0 + arow) * 1024 + k0 + axo,       aBase);
        gl16(encswz + (m0 + arow + 8) * 1024 + k0 + axo,   aBase + 512);
        gl16(whtswz + (long)(n0 + brow) * 1024 + k0 + axo,        bBase);
        gl16(whtswz + (long)(n0 + brow + 8) * 1024 + k0 + axo,    bBase + 512);
        gl16(whtswz + (long)(n0 + brow + 16) * 1024 + k0 + axo,   bBase + 1024);
        gl16(whtswz + (long)(n0 + brow + 24) * 1024 + k0 + axo,   bBase + 1536);
        __syncthreads();                       // drains vmcnt(0)
        #pragma unroll
        for (int kk = 0; kk < 2; ++kk) {
            const int kse = (kk * 32 + g * 8) ^ sx;
            s16x8 af[4], bfj[4];
            #pragma unroll
            for (int i = 0; i < 4; i++) af[i] = *(const s16x8*)&As[(wm * 64 + i * 16 + c) * 64 + kse];
            #pragma unroll
            for (int j = 0; j < 4; j++) bfj[j] = *(const s16x8*)&Bs[(wn * 64 + j * 16 + c) * 64 + kse];
            #pragma unroll
            for (int i = 0; i < 4; i++)
                #pragma unroll
                for (int j = 0; j < 4; j++)
                    acc[i][j] = __builtin_amdgcn_mfma_f32_16x16x32_bf16(af[i], bfj[j], acc[i][j], 0, 0, 0);
        }
    }
    // fused epilogue: v-weighted tanh partial sums for this nt
    float dfv[4], wcv[4], vvj[4];
    #pragma unroll
    for (int j = 0; j < 4; j++) {
        int col = n0 + wn * 64 + j * 16 + c;
        dfv[j] = decfeat[bblk * D2 + col];
        wcv[j] = Wc[col];
        vvj[j] = vvec[col];
    }
    float sAcc[4][4];
    #pragma unroll
    for (int i = 0; i < 4; i++) {
        #pragma unroll
        for (int r = 0; r < 4; r++) {
            const long m = m0 + wm * 64 + i * 16 + g * 4 + r;
            const float covm = cov[m];
            float su = 0.f;
            #pragma unroll
            for (int j = 0; j < 4; j++) {
                float e = acc[i][j][r] + dfv[j] + covm * wcv[j];
                su += tanh_fast(e) * vvj[j];
            }
            su += __shfl_xor(su, 1); su += __shfl_xor(su, 2);
            su += __shfl_xor(su, 4); su += __shfl_xor(su, 8);
            sAcc[i][r] = su;
        }
    }
    if (c == 0) {
        #pragma unroll
        for (int i = 0; i < 4; i++)
            #pragma unroll
            for (int r = 0; r < 4; r++)
                sred[wn][wm * 64 + i * 16 + g * 4 + r] = sAcc[i][r];
    }
    __syncthreads();
    if (tid < 128)
        scorep[(long)nt * MM + m0 + tid] = sred[0][tid] + sred[1][tid] + sred[2][tid] + sred[3][tid];
}

// ---------------------------------------------------------------- K5: softmax + mask renorm
__global__ void k_softmax(const float* __restrict__ scorep, const float* __restrict__ mask,
                          const float* __restrict__ cov, float* __restrict__ att,
                          float* __restrict__ covn) {
    int b = blockIdx.x, tid = threadIdx.x;  // 256 threads
    __shared__ float sm[8];
    float sv[4];
    float mx = -1e30f;
    #pragma unroll
    for (int i = 0; i < 4; i++) {
        long idx = (long)b * TT + tid + 256 * i;
        sv[i] = scorep[idx] + scorep[MM + idx] + scorep[2 * MM + idx] + scorep[3 * MM + idx];
        mx = fmaxf(mx, sv[i]);
    }
    for (int o = 32; o; o >>= 1) mx = fmaxf(mx, __shfl_xor(mx, o));
    if ((tid & 63) == 0) sm[tid >> 6] = mx;
    __syncthreads();
    mx = fmaxf(fmaxf(sm[0], sm[1]), fmaxf(sm[2], sm[3]));
    __syncthreads();
    float e[4]; float s = 0.f;
    #pragma unroll
    for (int i = 0; i < 4; i++) { e[i] = __expf(sv[i] - mx); s += e[i]; }
    for (int o = 32; o; o >>= 1) s += __shfl_xor(s, o);
    if ((tid & 63) == 0) sm[tid >> 6] = s;
    __syncthreads();
    s = sm[0] + sm[1] + sm[2] + sm[3];
    __syncthreads();
    float inv = 1.f / s;
    float am[4]; float s2 = 0.f;
    #pragma unroll
    for (int i = 0; i < 4; i++) { am[i] = e[i] * inv * mask[b * TT + tid + 256 * i]; s2 += am[i]; }
    for (int o = 32; o; o >>= 1) s2 += __shfl_xor(s2, o);
    if ((tid & 63) == 0) sm[tid >> 6] = s2;
    __syncthreads();
    s2 = sm[0] + sm[1] + sm[2] + sm[3];
    float inv2 = 1.f / s2;
    #pragma unroll
    for (int i = 0; i < 4; i++) {
        int t = tid + 256 * i;
        float a = am[i] * inv2;
        att[b * TT + t] = a;
        covn[b * TT + t] = cov[b * TT + t] + a;
    }
}

// ---------------------------------------------------------------- K6: context partials (bf16 enc) + reduce
__global__ void k_context(const unsigned short* __restrict__ encswz, const float* __restrict__ att,
                          float* __restrict__ part) {
    int b = blockIdx.x, tc = blockIdx.y;  // grid (32,16)
    int d4 = threadIdx.x;                 // 256 threads -> d = d4*4
    float a0 = 0, a1 = 0, a2 = 0, a3 = 0;
    const float* ab = att + b * TT;
    for (int t = tc * 64; t < tc * 64 + 64; ++t) {
        float a = ab[t];
        int sx = (t & 7) << 3;            // row swizzle: (b*1024+t)&7 == t&7
        const unsigned short* ep = encswz + ((long)b * TT + t) * D2 + ((d4 * 4) ^ sx);
        s16x4 ev = *(const s16x4*)ep;     // 8B read, swizzle is 8-elem granular -> contiguous
        a0 += a * bf2f((unsigned short)ev[0]); a1 += a * bf2f((unsigned short)ev[1]);
        a2 += a * bf2f((unsigned short)ev[2]); a3 += a * bf2f((unsigned short)ev[3]);
    }
    float* pp = part + (long)tc * BB * D2 + b * D2 + d4 * 4;
    pp[0] = a0; pp[1] = a1; pp[2] = a2; pp[3] = a3;
}

__global__ void k_ctxreduce(const float* __restrict__ part, float* __restrict__ ctx) {
    int i = blockIdx.x * 256 + threadIdx.x;  // 128 blocks
    float s = 0.f;
    #pragma unroll
    for (int p = 0; p < 16; p++) s += part[(long)p * BB * D2 + i];
    ctx[i] = s;
}

// ---------------------------------------------------------------- K7a: p_gen
__global__ void k_pgen(const float* __restrict__ ctx, const float* __restrict__ dechat,
                       const float* __restrict__ xbuf, const float* __restrict__ Wpg,
                       const float* __restrict__ bpg, float* __restrict__ pgen) {
    int b = blockIdx.x, tid = threadIdx.x;  // 256 threads
    __shared__ float sm[8];
    float acc = 0.f;
    for (int k = tid; k < D2; k += 256)
        acc += ctx[b * D2 + k] * Wpg[k] + dechat[b * D2 + k] * Wpg[D2 + k];
    acc += xbuf[b * EE + tid] * Wpg[2 * D2 + tid];
    for (int o = 32; o; o >>= 1) acc += __shfl_xor(acc, o);
    if ((tid & 63) == 0) sm[tid >> 6] = acc;
    __syncthreads();
    if (tid == 0) {
        float t = sm[0] + sm[1] + sm[2] + sm[3];
        pgen[b] = sigmoidf_(t + bpg[0]);
    }
}

// ---------------------------------------------------------------- K7b: hiddenT = ([h1|ctx] @ W_v1 + b_v1)^T
__global__ __launch_bounds__(512) void k_hidden(
    const float* __restrict__ h1, const float* __restrict__ ctx,
    const float* __restrict__ Wv1, const float* __restrict__ bv1,
    float* __restrict__ hiddenT) {
    __shared__ float xs[1536];
    __shared__ float sred[8][64];
    int b = blockIdx.x, n0 = blockIdx.y * 64;   // grid (32,8)
    int tid = threadIdx.x, nl = tid & 63, ks = tid >> 6;   // 8 x 192
    for (int i = tid; i < 1536; i += 512)
        xs[i] = (i < 512) ? h1[b * 512 + i] : ctx[b * 1024 + i - 512];
    __syncthreads();
    float acc = 0.f;
    for (int k = ks * 192; k < ks * 192 + 192; ++k)
        acc += xs[k] * Wv1[(long)k * 512 + n0 + nl];
    sred[ks][nl] = acc;
    __syncthreads();
    if (tid < 64) {
        int n = n0 + tid;
        float s = bv1[n];
        #pragma unroll
        for (int i = 0; i < 8; i++) s += sred[i][tid];
        hiddenT[n * 32 + b] = s;       // [k][b] layout for k_logits s_load path
    }
}

// ---------------------------------------------------------------- K8: logits = hidden @ W_v2 + b_v2
// 1 wave/block, lane = one v column, acc[32] in VGPRs, hiddenT via uniform (scalar) loads.
__global__ __launch_bounds__(64) void k_logits(const float* __restrict__ hiddenT,
                                               const float* __restrict__ Wv2,
                                               const float* __restrict__ bv2,
                                               float* __restrict__ logits) {
    int v = blockIdx.x * 64 + threadIdx.x;
    if (v >= VV) return;
    float acc[32];
    float bv = bv2[v];
    #pragma unroll
    for (int i = 0; i < 32; i++) acc[i] = bv;
    const float* wp = Wv2 + v;
    #pragma unroll 8
    for (int k = 0; k < 512; ++k) {
        float w = wp[(long)k * VV];
        const float* h = hiddenT + k * 32;   // block-uniform -> s_load
        #pragma unroll
        for (int b = 0; b < 32; b++) acc[b] += h[b] * w;
    }
    #pragma unroll
    for (int b = 0; b < 32; b++) logits[(long)b * VV + v] = acc[b];
}

// ---------------------------------------------------------------- K9: fused rowstats + vocab_final + scatter
__global__ __launch_bounds__(1024) void k_vocab_all(
    const float* __restrict__ logits, const float* __restrict__ pgen,
    const float* __restrict__ extraz, const float* __restrict__ att,
    const int* __restrict__ eiv, float* __restrict__ out0) {
    int b = blockIdx.x, tid = threadIdx.x;   // 32 blocks x 1024 thr
    __shared__ float sm[16];
    const float* lr = logits + (long)b * VV;
    float mx = -1e30f;
    for (int v = tid; v < VV; v += 1024) mx = fmaxf(mx, lr[v]);
    for (int o = 32; o; o >>= 1) mx = fmaxf(mx, __shfl_xor(mx, o));
    if ((tid & 63) == 0) sm[tid >> 6] = mx;
    __syncthreads();
    #pragma unroll
    for (int i = 0; i < 16; i++) mx = fmaxf(mx, sm[i]);
    __syncthreads();
    float s = 0.f;
    for (int v = tid; v < VV; v += 1024) s += __expf(lr[v] - mx);
    for (int o = 32; o; o >>= 1) s += __shfl_xor(s, o);
    if ((tid & 63) == 0) sm[tid >> 6] = s;
    __syncthreads();
    s = 0.f;
    #pragma unroll
    for (int i = 0; i < 16; i++) s += sm[i];
    float pg = pgen[b];
    float inv = pg / s;
    float* orow = out0 + (long)b * VE;
    for (int v = tid; v < VV; v += 1024) orow[v] = __expf(lr[v] - mx) * inv;
    if (tid < EXTRA) orow[VV + tid] = extraz[b * EXTRA + tid];
    __syncthreads();
    // pointer scatter (TT == 1024 == blockDim)
    float a = (1.f - pg) * att[b * TT + tid];
    atomicAdd(orow + eiv[b * TT + tid], a);
}

// ================================================================ host
extern "C" void kernel_launch(void* const* d_in, const int* in_sizes, int n_in,
                              void* d_out, int out_size, void* d_ws, size_t ws_size,
                              hipStream_t stream) {
    const int*   dec_in = (const int*)d_in[0];
    const float* h0     = (const float*)d_in[1];
    const float* c0     = (const float*)d_in[2];
    const float* enc    = (const float*)d_in[3];
    const float* mask   = (const float*)d_in[4];
    const float* pcv    = (const float*)d_in[5];
    const float* cov    = (const float*)d_in[6];
    const float* extraz = (const float*)d_in[7];
    const int*   eiv    = (const int*)d_in[8];
    /* d_in[9] = step (unused, training path) */
    const float* embt   = (const float*)d_in[10];
    const float* Wgx    = (const float*)d_in[11];
    const float* bgx    = (const float*)d_in[12];
    const float* Wih    = (const float*)d_in[13];
    const float* Whh    = (const float*)d_in[14];
    const float* bih    = (const float*)d_in[15];
    const float* bhh    = (const float*)d_in[16];
    const float* Wh     = (const float*)d_in[17];
    const float* Wc     = (const float*)d_in[18];
    const float* Ws     = (const float*)d_in[19];
    const float* bs     = (const float*)d_in[20];
    const float* vv     = (const float*)d_in[21];
    const float* Wpg    = (const float*)d_in[22];
    const float* bpg    = (const float*)d_in[23];
    const float* Wv1    = (const float*)d_in[24];
    const float* bv1    = (const float*)d_in[25];
    const float* Wv2    = (const float*)d_in[26];
    const float* bv2    = (const float*)d_in[27];

    float* out = (float*)d_out;
    float* out_vd  = out;
    float* out_h1  = out + (long)BB * VE;
    float* out_c1  = out_h1 + BB * DD;
    float* out_ctx = out_c1 + BB * DD;
    float* out_att = out_ctx + BB * D2;
    float* out_cov = out_att + BB * TT;

    char* p = (char*)d_ws;
    unsigned short* whtswz = (unsigned short*)p; p += (size_t)D2 * D2 * 2;      // 2 MB
    float* xbuf    = (float*)p;  p += (size_t)BB * EE * 4;
    float* dechat  = (float*)p;  p += (size_t)BB * D2 * 4;
    float* decfeat = (float*)p;  p += (size_t)BB * D2 * 4;
    float* scorep  = (float*)p;  p += (size_t)4 * MM * 4;                        // 512 KB
    float* pgen    = (float*)p;  p += 256;
    float* hiddenT = (float*)p;  p += (size_t)BB * DD * 4;
    float* ctxpart = (float*)p;  p += (size_t)16 * BB * D2 * 4;                  // 2 MB
    float* logits  = (float*)p;  p += (size_t)BB * VV * 4;                       // 6.43 MB
    unsigned short* encswz = (unsigned short*)p; p += (size_t)MM * D2 * 2;       // 67.1 MB

    k_transpose_wh<<<dim3(32, 32), dim3(32, 8), 0, stream>>>(Wh, whtswz);
    k_enc2bf<<<16384, 256, 0, stream>>>(enc, encswz);
    k_x<<<dim3(BB, 4), 512, 0, stream>>>(dec_in, pcv, embt, Wgx, bgx, xbuf);
    k_lstm<<<dim3(BB, 8), 512, 0, stream>>>(xbuf, h0, c0, Wih, Whh, bih, bhh, out_h1, out_c1, dechat);
    k_decfeat<<<dim3(BB, 16), 512, 0, stream>>>(dechat, Ws, bs, decfeat);
    k_scores<<<1024, 512, 0, stream>>>(encswz, whtswz, decfeat, cov, Wc, vv, scorep);
    k_softmax<<<BB, 256, 0, stream>>>(scorep, mask, cov, out_att, out_cov);
    k_context<<<dim3(BB, 16), 256, 0, stream>>>(encswz, out_att, ctxpart);
    k_ctxreduce<<<(BB * D2) / 256, 256, 0, stream>>>(ctxpart, out_ctx);
    k_pgen<<<BB, 256, 0, stream>>>(out_ctx, dechat, xbuf, Wpg, bpg, pgen);
    k_hidden<<<dim3(BB, 8), 512, 0, stream>>>(out_h1, out_ctx, Wv1, bv1, hiddenT);
    k_logits<<<786, 64, 0, stream>>>(hiddenT, Wv2, bv2, logits);
    k_vocab_all<<<BB, 1024, 0, stream>>>(logits, pgen, extraz, out_att, eiv, out_vd);
}